// Round 4
// baseline (235.440 us; speedup 1.0000x reference)
//
#include <hip/hip_runtime.h>

#pragma clang fp contract(off)

#define B_  512
#define N_  16384
#define A_  64
#define SL  8          // slices per batch (K1/K3)
#define EPT 8          // elements per thread (K1/K3)
#define CAP 2048

// ---------------- K1: distances -> 16-bit prefixes + per-batch histogram ---
__global__ __launch_bounds__(256) void k1_dist(
    const float* __restrict__ pos,  const float* __restrict__ mask,
    const float* __restrict__ apos, const float* __restrict__ amask,
    float* __restrict__ centws, unsigned* __restrict__ hist_g,
    unsigned short* __restrict__ ws16)
{
#pragma clang fp contract(off)
    __shared__ unsigned hist[2048];
    __shared__ float s_c[3];
    const int tid = threadIdx.x;
    const int blk = blockIdx.x;
    const int b = blk >> 3, sl = blk & 7;

#pragma unroll
    for (int i = 0; i < 8; ++i) hist[tid + i * 256] = 0u;

    // wave 0: centroid, bit-exact numpy reduction orders
    if (tid < 64) {
        const float* ap = apos  + (size_t)b * (A_ * 3);
        const float* am = amask + (size_t)b * A_;
        float comp = 0.0f, ms = 0.0f;
        if (tid < 3) {                       // axis=-2 sequential accumulate
            comp = ap[tid];
            for (int a = 1; a < A_; ++a) comp += ap[a * 3 + tid];
        }
        if (tid == 3) {                      // numpy pairwise-8 for n=64
            float r0 = am[0], r1 = am[1], r2 = am[2], r3 = am[3];
            float r4 = am[4], r5 = am[5], r6 = am[6], r7 = am[7];
            for (int i = 8; i < A_; i += 8) {
                r0 += am[i + 0]; r1 += am[i + 1]; r2 += am[i + 2]; r3 += am[i + 3];
                r4 += am[i + 4]; r5 += am[i + 5]; r6 += am[i + 6]; r7 += am[i + 7];
            }
            ms = ((r0 + r1) + (r2 + r3)) + ((r4 + r5) + (r6 + r7));
        }
        ms = __shfl(ms, 3, 64);
        if (tid < 3) s_c[tid] = comp / ms;   // correctly-rounded fp32 divide
    }
    __syncthreads();
    if (sl == 0 && tid < 3) centws[b * 4 + tid] = s_c[tid];

    const float cx = s_c[0], cy = s_c[1], cz = s_c[2];
    const int base = b * N_ + sl * 2048 + tid * EPT;
    const float* __restrict__ p = pos  + (size_t)base * 3;
    const float* __restrict__ m = mask + base;

    unsigned bits[EPT];
#pragma unroll
    for (int g = 0; g < 2; ++g) {
        const float4 pa = *(const float4*)(p + g * 12);
        const float4 pb = *(const float4*)(p + g * 12 + 4);
        const float4 pc = *(const float4*)(p + g * 12 + 8);
        const float4 mv = *(const float4*)(m + g * 4);
        const float px[4] = {pa.x, pa.w, pb.z, pc.y};
        const float py[4] = {pa.y, pb.x, pb.w, pc.z};
        const float pz[4] = {pa.z, pb.y, pc.x, pc.w};
        const float mm[4] = {mv.x, mv.y, mv.z, mv.w};
#pragma unroll
        for (int j = 0; j < 4; ++j) {
            float dx = cx - px[j], dy = cy - py[j], dz = cz - pz[j];
            float dx2 = dx * dx, dy2 = dy * dy, dz2 = dz * dz;
            float s = (dx2 + dy2) + dz2;     // numpy last-axis sum order
            s = s + 1e-12f;
            float d = sqrtf(s);              // correctly rounded
            d = d + (1.0f - mm[j]) * 1e10f;
            bits[g * 4 + j] = __float_as_uint(d);   // monotone, d > 0
        }
    }
#pragma unroll
    for (int x = 0; x < EPT; ++x) atomicAdd(&hist[bits[x] >> 21], 1u);

    uint4 pk;
    pk.x = (bits[0] >> 16) | ((bits[1] >> 16) << 16);
    pk.y = (bits[2] >> 16) | ((bits[3] >> 16) << 16);
    pk.z = (bits[4] >> 16) | ((bits[5] >> 16) << 16);
    pk.w = (bits[6] >> 16) | ((bits[7] >> 16) << 16);
    *(uint4*)(ws16 + base) = pk;

    __syncthreads();
#pragma unroll
    for (int i = 0; i < 8; ++i) {            // sparse flush: ~30 non-zero bins
        const unsigned v = hist[tid + i * 256];
        if (v) atomicAdd(&hist_g[b * 2048 + tid + i * 256], v);
    }
}

// ---------------- K2: exact per-batch threshold + boundary marking ---------
__global__ __launch_bounds__(1024) void k2_select(
    const float* __restrict__ pos, const float* __restrict__ mask,
    const int* __restrict__ topk_ptr, const float* __restrict__ centws,
    const unsigned* __restrict__ hist_g, unsigned* __restrict__ P16arr,
    unsigned short* __restrict__ ws16)
{
#pragma clang fp contract(off)
    __shared__ unsigned       hist2[32];
    __shared__ unsigned       cand_bits[CAP];
    __shared__ unsigned short cand_idx[CAP];
    __shared__ float          s_c[3];
    __shared__ unsigned       s_B11, s_cum, s_P16, s_j, s_ncand, s_k;

    const int tid = threadIdx.x;
    const int b   = blockIdx.x;
    if (tid < 32) hist2[tid] = 0u;
    if (tid < 3)  s_c[tid] = centws[b * 4 + tid];
    if (tid == 0) {
        s_ncand = 0u;
        int kk = *topk_ptr;
        if (kk < 0)  kk = 0;
        if (kk > N_) kk = N_;
        s_k = (unsigned)kk;
    }
    __syncthreads();
    const unsigned k = s_k;
    if (k == 0u) { if (tid == 0) P16arr[b] = 0u; return; }

    // level-1 + level-2 scan over the 2048-bin histogram (wave 0)
    if (tid < 64) {
        const uint4* hp = (const uint4*)(hist_g + (size_t)b * 2048 + tid * 32);
        unsigned ssum = 0;
#pragma unroll
        for (int r = 0; r < 8; ++r) { const uint4 h = hp[r]; ssum += h.x + h.y + h.z + h.w; }
        unsigned incl = ssum;
#pragma unroll
        for (int off = 1; off < 64; off <<= 1) {
            const unsigned v = (unsigned)__shfl_up((int)incl, off, 64);
            if (tid >= off) incl += v;
        }
        const unsigned long long bal = __ballot(incl >= k);
        const int g64 = __ffsll(bal) - 1;
        const unsigned cum64 = (unsigned)__shfl((int)(incl - ssum), g64, 64);
        const unsigned h2 = (tid < 32) ? hist_g[(size_t)b * 2048 + g64 * 32 + tid] : 0u;
        unsigned incl2 = h2;
#pragma unroll
        for (int off = 1; off < 64; off <<= 1) {
            const unsigned v = (unsigned)__shfl_up((int)incl2, off, 64);
            if (tid >= off) incl2 += v;
        }
        const unsigned long long bal2 = __ballot(tid < 32 && (cum64 + incl2 >= k));
        const int sb = __ffsll(bal2) - 1;
        const unsigned cum = cum64 + (unsigned)__shfl((int)(incl2 - h2), sb, 64);
        if (tid == 0) { s_B11 = (unsigned)(g64 * 32 + sb); s_cum = cum; }
    }
    __syncthreads();
    const unsigned B11 = s_B11;

    // pass 1 over prefixes: refine low 5 bits
    unsigned short* __restrict__ w16 = ws16 + (size_t)b * N_;
    const uint4* wp = (const uint4*)(w16 + (size_t)tid * 16);
    const uint4 a0 = wp[0];
    const uint4 a1 = wp[1];
    const unsigned pref[16] = {
        a0.x & 0xFFFFu, a0.x >> 16, a0.y & 0xFFFFu, a0.y >> 16,
        a0.z & 0xFFFFu, a0.z >> 16, a0.w & 0xFFFFu, a0.w >> 16,
        a1.x & 0xFFFFu, a1.x >> 16, a1.y & 0xFFFFu, a1.y >> 16,
        a1.z & 0xFFFFu, a1.z >> 16, a1.w & 0xFFFFu, a1.w >> 16 };
#pragma unroll
    for (int x = 0; x < 16; ++x)
        if ((pref[x] >> 5) == B11) atomicAdd(&hist2[pref[x] & 31u], 1u);
    __syncthreads();
    if (tid < 64) {
        const unsigned h = (tid < 32) ? hist2[tid] : 0u;
        unsigned incl = h;
#pragma unroll
        for (int off = 1; off < 64; off <<= 1) {
            const unsigned v = (unsigned)__shfl_up((int)incl, off, 64);
            if (tid >= off) incl += v;
        }
        const unsigned cum0 = s_cum;
        const unsigned long long bal = __ballot(tid < 32 && (cum0 + incl >= k));
        const int sb = __ffsll(bal) - 1;
        const unsigned cumx = cum0 + (unsigned)__shfl((int)(incl - h), sb, 64);
        if (tid == 0) { s_P16 = (B11 << 5) | (unsigned)sb; s_j = k - cumx; }
    }
    __syncthreads();
    const unsigned P16 = s_P16, j = s_j;

    // pass 2: gather ==P16 candidates, recompute full bits (bit-exact)
    const float cx = s_c[0], cy = s_c[1], cz = s_c[2];
    const float* __restrict__ p = pos  + (size_t)b * N_ * 3;
    const float* __restrict__ m = mask + (size_t)b * N_;
#pragma unroll
    for (int x = 0; x < 16; ++x) {
        if (pref[x] == P16) {
            const unsigned w = atomicAdd(&s_ncand, 1u);
            if (w < CAP) {
                const int i = tid * 16 + x;
                float dx = cx - p[i * 3], dy = cy - p[i * 3 + 1], dz = cz - p[i * 3 + 2];
                float dx2 = dx * dx, dy2 = dy * dy, dz2 = dz * dz;
                float s = (dx2 + dy2) + dz2;
                s = s + 1e-12f;
                float d = sqrtf(s);
                d = d + (1.0f - m[i]) * 1e10f;
                cand_bits[w] = __float_as_uint(d);
                cand_idx[w]  = (unsigned short)i;
            }
        }
    }
    __syncthreads();

    // rank candidates (tie -> lowest index); mark rank<j in ws16
    const unsigned c = min(s_ncand, (unsigned)CAP);
    for (unsigned t = tid; t < c; t += 1024) {
        const unsigned bt = cand_bits[t];
        const unsigned it = cand_idx[t];
        unsigned rank = 0;
        for (unsigned u = 0; u < c; ++u) {
            const unsigned bu = cand_bits[u];
            rank += (bu < bt) || (bu == bt && (unsigned)cand_idx[u] < it);
        }
        if (rank < j) w16[it] = 0;   // 0 < P16 always (d >= 1e-6)
    }
    if (tid == 0) P16arr[b] = P16;
}

// ---------------- K3: stream prefixes + mask -> both outputs ---------------
__global__ __launch_bounds__(256) void k3_write(
    const float* __restrict__ mask, const unsigned* __restrict__ P16arr,
    const unsigned short* __restrict__ ws16,
    float* __restrict__ out0, float* __restrict__ out1)
{
    const int tid = threadIdx.x;
    const int blk = blockIdx.x;
    const int b = blk >> 3, sl = blk & 7;
    const int base = b * N_ + sl * 2048 + tid * EPT;
    const unsigned P16 = P16arr[b];

    const uint4  pk = *(const uint4*)(ws16 + base);
    const float4 m0 = *(const float4*)(mask + base);
    const float4 m1 = *(const float4*)(mask + base + 4);
    const unsigned pre[8] = {pk.x & 0xFFFFu, pk.x >> 16, pk.y & 0xFFFFu, pk.y >> 16,
                             pk.z & 0xFFFFu, pk.z >> 16, pk.w & 0xFFFFu, pk.w >> 16};
    const float mm[8] = {m0.x, m0.y, m0.z, m0.w, m1.x, m1.y, m1.z, m1.w};

    float o0v[8], o1v[8];
#pragma unroll
    for (int x = 0; x < 8; ++x) {
        const bool sel = pre[x] < P16;
        o0v[x] = sel ? 0.0f  : mm[x];
        o1v[x] = sel ? 32.0f : (1.0f - mm[x]);
    }
    *(float4*)(out0 + base)     = make_float4(o0v[0], o0v[1], o0v[2], o0v[3]);
    *(float4*)(out0 + base + 4) = make_float4(o0v[4], o0v[5], o0v[6], o0v[7]);
    *(float4*)(out1 + base)     = make_float4(o1v[0], o1v[1], o1v[2], o1v[3]);
    *(float4*)(out1 + base + 4) = make_float4(o1v[4], o1v[5], o1v[6], o1v[7]);
}

extern "C" void kernel_launch(void* const* d_in, const int* in_sizes, int n_in,
                              void* d_out, int out_size, void* d_ws, size_t ws_size,
                              hipStream_t stream) {
    const float* pos   = (const float*)d_in[0];   // [B,N,3]
    const float* rmask = (const float*)d_in[1];   // [B,N]
    const float* apos  = (const float*)d_in[2];   // [B,A,3]
    const float* amask = (const float*)d_in[3];   // [B,A]
    // d_in[4] = max_p (unused by the reference outputs)
    const int*   topk  = (const int*)d_in[5];

    float* out0 = (float*)d_out;
    float* out1 = out0 + (size_t)B_ * N_;

    char* ws = (char*)d_ws;
    float*          centws = (float*)ws;                                  // 8 KB
    unsigned*       P16arr = (unsigned*)(ws + 8192);                      // 2 KB
    unsigned*       hist_g = (unsigned*)(ws + 16384);                     // 4 MB
    unsigned short* ws16   = (unsigned short*)(ws + 16384 + (size_t)B_ * 2048 * 4); // 16 MB

    hipMemsetAsync(hist_g, 0, (size_t)B_ * 2048 * sizeof(unsigned), stream);
    k1_dist  <<<B_ * SL, 256,  0, stream>>>(pos, rmask, apos, amask, centws, hist_g, ws16);
    k2_select<<<B_,      1024, 0, stream>>>(pos, rmask, topk, centws, hist_g, P16arr, ws16);
    k3_write <<<B_ * SL, 256,  0, stream>>>(rmask, P16arr, ws16, out0, out1);
}

// Round 5
// 214.113 us; speedup vs baseline: 1.0996x; 1.0996x over previous
//
#include <hip/hip_runtime.h>

#pragma clang fp contract(off)

#define B_     512
#define N_     16384
#define A_     64
#define TPB    1024
#define CHUNK  1024
#define NCHUNK 16
#define CAP    2048

// One block per batch. All global loads fully coalesced (pos staged through
// LDS in double-buffered 12 KB chunks). Exact top-k via 11-bit + 5-bit
// histogram select on fp32 bit patterns (monotone for d >= 0), boundary
// resolved by full-bits rank with index tie-break. Bit-exact numpy math.
__global__ __launch_bounds__(TPB, 8) void fused_kernel(
    const float* __restrict__ pos,   const float* __restrict__ mask,
    const float* __restrict__ apos,  const float* __restrict__ amask,
    const int*   __restrict__ topk_ptr,
    float* __restrict__ out0, float* __restrict__ out1)
{
#pragma clang fp contract(off)
    __shared__ float          s_pos[2][3 * CHUNK];   // 24 KB staging (dbuf)
    __shared__ unsigned short dist16[N_];            // 32 KB 16-bit prefixes
    __shared__ unsigned       hist[2048];            // 8 KB 11-bit histogram
    __shared__ unsigned       hist2[32];             // 5-bit refinement
    __shared__ unsigned       cand_bits[CAP];        // 8 KB boundary cands
    __shared__ unsigned short cand_idx[CAP];         // 4 KB
    __shared__ float          s_c[3];
    __shared__ unsigned       s_B11, s_cum, s_P16, s_j, s_ncand, s_k;

    const int tid = threadIdx.x;
    const int b   = blockIdx.x;
    const float* __restrict__ p = pos  + (size_t)b * N_ * 3;
    const float* __restrict__ m = mask + (size_t)b * N_;

    hist[tid]        = 0u;
    hist[tid + 1024] = 0u;
    if (tid < 32) hist2[tid] = 0u;
    if (tid == 0) s_ncand = 0u;

    // ---- wave 0: centroid, bit-exact numpy reduction orders ---------------
    if (tid < 64) {
        const float* ap = apos  + (size_t)b * (A_ * 3);
        const float* am = amask + (size_t)b * A_;
        float comp = 0.0f, ms = 0.0f;
        if (tid < 3) {                       // axis=-2 sequential accumulate
            comp = ap[tid];
            for (int a = 1; a < A_; ++a) comp += ap[a * 3 + tid];
        }
        if (tid == 3) {                      // numpy pairwise-8 for n=64
            float r0 = am[0], r1 = am[1], r2 = am[2], r3 = am[3];
            float r4 = am[4], r5 = am[5], r6 = am[6], r7 = am[7];
            for (int i = 8; i < A_; i += 8) {
                r0 += am[i + 0]; r1 += am[i + 1]; r2 += am[i + 2]; r3 += am[i + 3];
                r4 += am[i + 4]; r5 += am[i + 5]; r6 += am[i + 6]; r7 += am[i + 7];
            }
            ms = ((r0 + r1) + (r2 + r3)) + ((r4 + r5) + (r6 + r7));
        }
        ms = __shfl(ms, 3, 64);
        if (tid < 3) s_c[tid] = comp / ms;   // correctly-rounded fp32 divide
        if (tid == 4) {
            int kk = *topk_ptr;
            if (kk < 0)  kk = 0;
            if (kk > N_) kk = N_;
            s_k = (unsigned)kk;
        }
    }
    __syncthreads();

    const float cx = s_c[0], cy = s_c[1], cz = s_c[2];
    const unsigned k = s_k;

    // ---- Phase A: coalesced-staged distances, prefixes to LDS -------------
    for (int c = 0; c < NCHUNK; ++c) {
        float* sb = s_pos[c & 1];
        const float* src = p + c * (3 * CHUNK);
        sb[tid]        = src[tid];           // 3 coalesced dword wave-loads
        sb[tid + 1024] = src[tid + 1024];
        sb[tid + 2048] = src[tid + 2048];
        const float mv = m[c * CHUNK + tid]; // coalesced
        __syncthreads();                     // stage visible (1 barrier/chunk)

        const float px = sb[3 * tid + 0];    // stride-3: 2 lanes/bank = free
        const float py = sb[3 * tid + 1];
        const float pz = sb[3 * tid + 2];
        float dx = cx - px, dy = cy - py, dz = cz - pz;
        float dx2 = dx * dx, dy2 = dy * dy, dz2 = dz * dz;
        float s = (dx2 + dy2) + dz2;         // numpy last-axis sum order
        s = s + 1e-12f;
        float d = sqrtf(s);                  // correctly rounded
        d = d + (1.0f - mv) * 1e10f;
        const unsigned bits = __float_as_uint(d);  // monotone, d > 0
        dist16[c * CHUNK + tid] = (unsigned short)(bits >> 16);
        atomicAdd(&hist[bits >> 21], 1u);
    }
    __syncthreads();

    if (k > 0) {
        // ---- Phase B: wave-0 two-level scan over 2048-bin histogram ------
        if (tid < 64) {
            const uint4* hp = (const uint4*)&hist[tid * 32];
            unsigned ssum = 0;
#pragma unroll
            for (int r = 0; r < 8; ++r) {
                const uint4 h = hp[r];
                ssum += h.x + h.y + h.z + h.w;
            }
            unsigned incl = ssum;
#pragma unroll
            for (int off = 1; off < 64; off <<= 1) {
                const unsigned v = (unsigned)__shfl_up((int)incl, off, 64);
                if (tid >= off) incl += v;
            }
            const unsigned long long bal = __ballot(incl >= k);
            const int g64 = __ffsll(bal) - 1;
            const unsigned cum64 = (unsigned)__shfl((int)(incl - ssum), g64, 64);
            const unsigned h2 = (tid < 32) ? hist[g64 * 32 + tid] : 0u;
            unsigned incl2 = h2;
#pragma unroll
            for (int off = 1; off < 64; off <<= 1) {
                const unsigned v = (unsigned)__shfl_up((int)incl2, off, 64);
                if (tid >= off) incl2 += v;
            }
            const unsigned long long bal2 =
                __ballot(tid < 32 && (cum64 + incl2 >= k));
            const int sb2 = __ffsll(bal2) - 1;
            const unsigned cum =
                cum64 + (unsigned)__shfl((int)(incl2 - h2), sb2, 64);
            if (tid == 0) { s_B11 = (unsigned)(g64 * 32 + sb2); s_cum = cum; }
        }
        __syncthreads();
        const unsigned B11 = s_B11;

        // ---- Phase C: refine low-5 bits of the 16-bit prefix -------------
        for (int c = 0; c < NCHUNK; ++c) {
            const unsigned pref = dist16[c * CHUNK + tid];
            if ((pref >> 5) == B11) atomicAdd(&hist2[pref & 31u], 1u);
        }
        __syncthreads();
        if (tid < 64) {
            const unsigned h = (tid < 32) ? hist2[tid] : 0u;
            unsigned incl = h;
#pragma unroll
            for (int off = 1; off < 64; off <<= 1) {
                const unsigned v = (unsigned)__shfl_up((int)incl, off, 64);
                if (tid >= off) incl += v;
            }
            const unsigned cum0 = s_cum;
            const unsigned long long bal =
                __ballot(tid < 32 && (cum0 + incl >= k));
            const int sb2 = __ffsll(bal) - 1;
            const unsigned cumx =
                cum0 + (unsigned)__shfl((int)(incl - h), sb2, 64);
            if (tid == 0) { s_P16 = (B11 << 5) | (unsigned)sb2; s_j = k - cumx; }
        }
        __syncthreads();
        const unsigned P16 = s_P16, j = s_j;

        // ---- Phase D: gather ==P16 candidates, recompute full bits -------
        for (int c = 0; c < NCHUNK; ++c) {
            const int i = c * CHUNK + tid;
            if (dist16[i] == (unsigned short)P16) {
                const unsigned w = atomicAdd(&s_ncand, 1u);
                if (w < CAP) {
                    float dx = cx - p[i * 3], dy = cy - p[i * 3 + 1];
                    float dz = cz - p[i * 3 + 2];
                    float dx2 = dx * dx, dy2 = dy * dy, dz2 = dz * dz;
                    float s = (dx2 + dy2) + dz2;
                    s = s + 1e-12f;
                    float d = sqrtf(s);
                    d = d + (1.0f - m[i]) * 1e10f;
                    cand_bits[w] = __float_as_uint(d);
                    cand_idx[w]  = (unsigned short)i;
                }
            }
        }
        __syncthreads();

        // ---- Phase E: rank (tie -> lowest index); mark rank<j ------------
        const unsigned c = min(s_ncand, (unsigned)CAP);
        for (unsigned t = tid; t < c; t += TPB) {
            const unsigned bt = cand_bits[t];
            const unsigned it = cand_idx[t];
            unsigned rank = 0;
            for (unsigned u = 0; u < c; ++u) {
                const unsigned bu = cand_bits[u];
                rank += (bu < bt) || (bu == bt && (unsigned)cand_idx[u] < it);
            }
            if (rank < j) dist16[it] = 0;   // 0 < P16 always (d >= 1e-6)
        }
        __syncthreads();
    }

    // ---- Phase F: stream outputs (mask re-read is L3-hot) -----------------
    const unsigned P16f = (k > 0) ? s_P16 : 0u;
#pragma unroll
    for (int c = 0; c < 4; ++c) {
        const int i0 = c * 4096 + tid * 4;
        const ushort4 dv = *(const ushort4*)&dist16[i0];
        const float4  mv = *(const float4*)(m + i0);
        const unsigned pre[4] = {dv.x, dv.y, dv.z, dv.w};
        const float    mm[4]  = {mv.x, mv.y, mv.z, mv.w};
        float4 o0, o1;
        float* o0p = &o0.x; float* o1p = &o1.x;
#pragma unroll
        for (int jj = 0; jj < 4; ++jj) {
            const bool sel = pre[jj] < P16f;
            o0p[jj] = sel ? 0.0f  : mm[jj];
            o1p[jj] = sel ? 32.0f : (1.0f - mm[jj]);
        }
        *(float4*)(out0 + (size_t)b * N_ + i0) = o0;
        *(float4*)(out1 + (size_t)b * N_ + i0) = o1;
    }
}

extern "C" void kernel_launch(void* const* d_in, const int* in_sizes, int n_in,
                              void* d_out, int out_size, void* d_ws, size_t ws_size,
                              hipStream_t stream) {
    const float* pos   = (const float*)d_in[0];   // [B,N,3]
    const float* rmask = (const float*)d_in[1];   // [B,N]
    const float* apos  = (const float*)d_in[2];   // [B,A,3]
    const float* amask = (const float*)d_in[3];   // [B,A]
    // d_in[4] = max_p (unused by the reference outputs)
    const int*   topk  = (const int*)d_in[5];

    float* out0 = (float*)d_out;
    float* out1 = out0 + (size_t)B_ * N_;

    fused_kernel<<<B_, TPB, 0, stream>>>(pos, rmask, apos, amask, topk, out0, out1);
}